// Round 1
// baseline (23441.100 us; speedup 1.0000x reference)
//
#include <hip/hip_runtime.h>
#include <hip/hip_bf16.h>
#include <math.h>

// Problem constants
#define VB   50000
#define EE   256
#define UU   512
#define BB   256
#define TT   256
#define G4   2048   // 4*U

// Tiling
#define BM   32     // batch rows per block
#define BU   16     // u-columns per block (x4 gates = 64 z-cols)
#define KB   64     // K chunk
#define LDST 68     // LDS row stride in floats (17*16B: aligned, conflict-light)

__device__ __forceinline__ float sigf(float x) { return 1.0f / (1.0f + expf(-x)); }

// One LSTM layer for one time step.
// z[b][g*512+u] = bias + sum_k A[b][k] * W[k][g*512+u],
// A = concat(x_part (Kx wide), h_prev (512 wide)).
// x_part: layer0 -> emb[tokens[b][t]]; layer1 -> xin (= h0 just computed).
__global__ __launch_bounds__(256) void lstm_step(
    const float* __restrict__ Wx,   // [Kx, 2048]
    const float* __restrict__ Wh,   // [512, 2048]
    const float* __restrict__ bias, // [2048]
    const float* __restrict__ xin,  // [B,512] or nullptr
    const int*   __restrict__ tokens, // [B,T] or nullptr
    const float* __restrict__ emb,  // [V,E]
    int t,
    const float* __restrict__ h_prev, // [B,512]
    float*       __restrict__ h_new,  // [B,512]
    float*       __restrict__ c_st,   // [B,512] in-place
    int Kx)
{
    __shared__ float As[BM * LDST];   // A tile [32 rows][64 k]
    __shared__ float Bs[64 * LDST];   // W tile [64 j][64 k]  (j = g*16 + u_local)
    __shared__ int   tok[BM];

    const int tid   = threadIdx.x;
    const int u0    = blockIdx.x * BU;   // 32 u-tiles
    const int brow0 = blockIdx.y * BM;   // 8 b-tiles

    if (tokens != nullptr && tid < BM) tok[tid] = tokens[(brow0 + tid) * TT + t];
    __syncthreads();

    const int arow = tid >> 3;   // 0..31
    const int af   = tid & 7;    // 0..7
    const int bkr  = tid >> 2;   // 0..63  (k row of W tile)
    const int bq   = tid & 3;    // 0..3   (u quad)
    const int uidx = tid & 15;   // owned u within tile
    const int bidx = tid >> 4;   // 0..15; owns rows bidx, bidx+16

    float acc[2][4] = {{0.f,0.f,0.f,0.f},{0.f,0.f,0.f,0.f}};
    const int Ktot = Kx + UU;

    for (int kc = 0; kc < Ktot; kc += KB) {
        // ---- stage A tile: 2 float4 per thread ----
        #pragma unroll
        for (int rep = 0; rep < 2; rep++) {
            int koff = (af + rep * 8) * 4;      // 0..60 step 4
            int kk   = kc + koff;
            const float* src;
            if (kk < Kx) {
                src = (tokens != nullptr)
                    ? (emb + (size_t)tok[arow] * EE + kk)
                    : (xin + (size_t)(brow0 + arow) * UU + kk);
            } else {
                src = h_prev + (size_t)(brow0 + arow) * UU + (kk - Kx);
            }
            float4 v = *(const float4*)src;
            *(float4*)&As[arow * LDST + koff] = v;
        }
        // ---- stage W tile (transposed to [j][k]): 4 float4 per thread ----
        {
            int kk = kc + bkr;
            const float* wbase = (kk < Kx) ? (Wx + (size_t)kk * G4)
                                           : (Wh + (size_t)(kk - Kx) * G4);
            #pragma unroll
            for (int g = 0; g < 4; g++) {
                float4 v = *(const float4*)(wbase + g * UU + u0 + bq * 4);
                int jb = g * 16 + bq * 4;
                Bs[(jb + 0) * LDST + bkr] = v.x;
                Bs[(jb + 1) * LDST + bkr] = v.y;
                Bs[(jb + 2) * LDST + bkr] = v.z;
                Bs[(jb + 3) * LDST + bkr] = v.w;
            }
        }
        __syncthreads();
        // ---- inner product over this K chunk ----
        #pragma unroll
        for (int k = 0; k < KB; k += 4) {
            float4 a0 = *(float4*)&As[ bidx       * LDST + k];
            float4 a1 = *(float4*)&As[(bidx + 16) * LDST + k];
            #pragma unroll
            for (int g = 0; g < 4; g++) {
                float4 w = *(float4*)&Bs[(g * 16 + uidx) * LDST + k];
                acc[0][g] = fmaf(a0.x, w.x, acc[0][g]);
                acc[0][g] = fmaf(a0.y, w.y, acc[0][g]);
                acc[0][g] = fmaf(a0.z, w.z, acc[0][g]);
                acc[0][g] = fmaf(a0.w, w.w, acc[0][g]);
                acc[1][g] = fmaf(a1.x, w.x, acc[1][g]);
                acc[1][g] = fmaf(a1.y, w.y, acc[1][g]);
                acc[1][g] = fmaf(a1.z, w.z, acc[1][g]);
                acc[1][g] = fmaf(a1.w, w.w, acc[1][g]);
            }
        }
        __syncthreads();
    }

    // ---- gates: i,f,g,o at columns u, u+512, u+1024, u+1536 ----
    const int u = u0 + uidx;
    const float bi = bias[u];
    const float bf = bias[UU + u];
    const float bg = bias[2 * UU + u];
    const float bo = bias[3 * UU + u];
    #pragma unroll
    for (int r = 0; r < 2; r++) {
        int b = brow0 + bidx + r * 16;
        size_t idx = (size_t)b * UU + u;
        float zi = acc[r][0] + bi;
        float zf = acc[r][1] + bf;
        float zg = acc[r][2] + bg;
        float zo = acc[r][3] + bo;
        float cn = sigf(zf) * c_st[idx] + sigf(zi) * tanhf(zg);
        c_st[idx]  = cn;
        h_new[idx] = sigf(zo) * tanhf(cn);
    }
}

// out[b] = sigmoid(dot(h1[b], Wd) + bd)
__global__ __launch_bounds__(64) void dense_out(
    const float* __restrict__ h, const float* __restrict__ Wd,
    const float* __restrict__ bd, float* __restrict__ out)
{
    int b = blockIdx.x;
    int lane = threadIdx.x;  // 64
    float s = 0.f;
    #pragma unroll
    for (int k = lane; k < UU; k += 64) s += h[(size_t)b * UU + k] * Wd[k];
    #pragma unroll
    for (int off = 32; off > 0; off >>= 1) s += __shfl_down(s, off);
    if (lane == 0) out[b] = sigf(s + bd[0]);
}

extern "C" void kernel_launch(void* const* d_in, const int* in_sizes, int n_in,
                              void* d_out, int out_size, void* d_ws, size_t ws_size,
                              hipStream_t stream) {
    const int*   tokens = (const int*)  d_in[0];
    const float* emb    = (const float*)d_in[1];
    const float* W0     = (const float*)d_in[2];
    const float* U0     = (const float*)d_in[3];
    const float* b0     = (const float*)d_in[4];
    const float* W1     = (const float*)d_in[5];
    const float* U1     = (const float*)d_in[6];
    const float* b1     = (const float*)d_in[7];
    const float* Wd     = (const float*)d_in[8];
    const float* bd     = (const float*)d_in[9];
    float* out = (float*)d_out;

    // Workspace layout (floats), S = B*U = 131072:
    // [h0_a][h1_a][c0][c1][h0_b][h1_b]  -> first 4 segments zero-initialized
    const size_t S = (size_t)BB * UU;
    float* ws = (float*)d_ws;
    float* h0a = ws;
    float* h1a = ws + S;
    float* c0  = ws + 2 * S;
    float* c1  = ws + 3 * S;
    float* h0b = ws + 4 * S;
    float* h1b = ws + 5 * S;

    hipMemsetAsync(d_ws, 0, 4 * S * sizeof(float), stream);

    dim3 grid(UU / BU, BB / BM);  // (32, 8) = 256 blocks
    dim3 block(256);

    float* h0_in = h0a; float* h0_out = h0b;
    float* h1_in = h1a; float* h1_out = h1b;

    for (int t = 0; t < TT; t++) {
        // layer 0: x from embedding gather, Kx = 256
        lstm_step<<<grid, block, 0, stream>>>(W0, U0, b0, nullptr, tokens, emb, t,
                                              h0_in, h0_out, c0, EE);
        // layer 1: x = h0 (just computed), Kx = 512
        lstm_step<<<grid, block, 0, stream>>>(W1, U1, b1, h0_out, nullptr, nullptr, t,
                                              h1_in, h1_out, c1, UU);
        float* tmp;
        tmp = h0_in; h0_in = h0_out; h0_out = tmp;
        tmp = h1_in; h1_in = h1_out; h1_out = tmp;
    }

    dense_out<<<dim3(BB), dim3(64), 0, stream>>>(h1_in, Wd, bd, out);
}

// Round 2
// 13010.956 us; speedup vs baseline: 1.8016x; 1.8016x over previous
//
#include <hip/hip_runtime.h>
#include <hip/hip_bf16.h>
#include <hip/hip_cooperative_groups.h>
#include <math.h>

namespace cg = cooperative_groups;

#define VB   50000
#define EE   256
#define UU   512
#define BB   256
#define TT   256
#define G4   2048

typedef __attribute__((ext_vector_type(8))) short short8;
typedef __attribute__((ext_vector_type(4))) float f32x4;

union U8 { short8 v; short s[8]; };

__device__ __forceinline__ float sigf(float x) { return 1.0f / (1.0f + expf(-x)); }

__device__ __forceinline__ short f2bf(float f) {
    __hip_bfloat16 h = __float2bfloat16(f);   // RNE
    short s; __builtin_memcpy(&s, &h, 2); return s;
}
__device__ __forceinline__ float bf2f(unsigned short u) {
    unsigned int x = ((unsigned int)u) << 16;
    float f; __builtin_memcpy(&f, &x, 4); return f;
}

// ---------- pre-pass: transpose+convert W [rows][2048] fp32 -> out[c][koff+k] bf16 ----------
__global__ __launch_bounds__(256) void wtrans(const float* __restrict__ in, int rows,
                                              unsigned short* __restrict__ out,
                                              int Kout, int koff) {
    __shared__ float tl[32][33];
    int tx = threadIdx.x, ty = threadIdx.y;
    int c0 = blockIdx.x * 32, k0 = blockIdx.y * 32;
    #pragma unroll
    for (int i = 0; i < 4; i++)
        tl[ty + i * 8][tx] = in[(size_t)(k0 + ty + i * 8) * G4 + c0 + tx];
    __syncthreads();
    #pragma unroll
    for (int i = 0; i < 4; i++)
        out[(size_t)(c0 + ty + i * 8) * Kout + koff + k0 + tx] = (unsigned short)f2bf(tl[tx][ty + i * 8]);
}

// ---------- pre-pass: gather embeddings -> xbf[t][b][k] bf16 ----------
__global__ __launch_bounds__(64) void xgather(const int* __restrict__ tokens,
                                              const float* __restrict__ emb,
                                              unsigned short* __restrict__ xbf) {
    int flat = blockIdx.x;
    int b = flat & 255, t = flat >> 8;
    int tok = tokens[b * TT + t];
    float4 v = ((const float4*)(emb + (size_t)tok * EE))[threadIdx.x];
    ushort4 o;
    o.x = (unsigned short)f2bf(v.x); o.y = (unsigned short)f2bf(v.y);
    o.z = (unsigned short)f2bf(v.z); o.w = (unsigned short)f2bf(v.w);
    ((ushort4*)(xbf + ((size_t)t * BB + b) * EE))[threadIdx.x] = o;
}

// ---------- persistent 2-layer LSTM, software-pipelined, 1 grid-sync per step ----------
// blocks 0..127: layer0, u0=bid*4, K=768  (A = [x_p(256) | h0(512)])
// blocks 128..255: layer1, u0=(bid-128)*4, K=1024 (A = [h0(512) | h1(512)])
// 16 z-cols per block: n = g*4+j -> global col g*512+u0+j. c-state fp32 in registers.
__global__ __launch_bounds__(256, 1) void rnn_persist(
    const unsigned short* __restrict__ Wt0,  // [2048][768]
    const unsigned short* __restrict__ Wt1,  // [2048][1024]
    const unsigned short* __restrict__ xbf,  // [256][256][256] or unused
    const int* __restrict__ tokens, const float* __restrict__ emb,
    const float* __restrict__ b0, const float* __restrict__ b1,
    unsigned short* __restrict__ h0buf,      // [2][256][512]
    unsigned short* __restrict__ h1buf,      // [2][256][512]
    int use_xbf)
{
    cg::grid_group grid = cg::this_grid();

    __shared__ unsigned short wlds[16 * 1032];  // [n][k], stride K+8
    __shared__ float zbuf[256 * 17];
    __shared__ int tokl[256];

    const int tid = threadIdx.x;
    const int bid = blockIdx.x;
    const int layer = (bid >= 128) ? 1 : 0;
    const int u0 = (bid & 127) * 4;
    const int K = layer ? 1024 : 768;
    const int stride = K + 8;
    const unsigned short* Wt = layer ? Wt1 : Wt0;

    // load this block's 16 weight columns into LDS (resident all 256 steps)
    for (int idx = tid; idx < 16 * (K / 8); idx += 256) {
        int n = idx / (K / 8);
        int kk = (idx - n * (K / 8)) * 8;
        int g = n >> 2, j = n & 3;
        int c = g * UU + u0 + j;
        short8 v = *(const short8*)(Wt + (size_t)c * K + kk);
        *(short8*)&wlds[n * stride + kk] = v;
    }
    // per-thread bias (thread tid gates batch row b=tid, u = u0+j)
    const float* bR = layer ? b1 : b0;
    float bias_r[4][4];
    #pragma unroll
    for (int g = 0; g < 4; g++)
        #pragma unroll
        for (int j = 0; j < 4; j++)
            bias_r[g][j] = bR[g * UU + u0 + j];
    float cstate[4] = {0.f, 0.f, 0.f, 0.f};
    __syncthreads();

    const int lane = tid & 63;
    const int w = tid >> 6;      // wave 0..3, owns batch rows [w*64, w*64+64)
    const int n16 = lane & 15;
    const int q = lane >> 4;
    const int q8 = q * 8;

    int mrow[4];
    #pragma unroll
    for (int mt = 0; mt < 4; mt++) mrow[mt] = w * 64 + mt * 16 + n16;

    const size_t HS = (size_t)BB * UU;

    for (int p = 0; p <= TT; p++) {
        const bool active = layer ? (p >= 1) : (p < TT);
        if (active) {
            const unsigned short* h0r = h0buf + (size_t)(p & 1) * HS;
            unsigned short* hw = layer ? (h1buf + (size_t)(p & 1) * HS)
                                       : (h0buf + (size_t)((p + 1) & 1) * HS);
            const unsigned short* h1r = h1buf + (size_t)((p - 1) & 1) * HS;

            if (layer == 0 && !use_xbf) {
                tokl[tid] = tokens[tid * TT + p];
                __syncthreads();
            }

            f32x4 acc[4];
            #pragma unroll
            for (int mt = 0; mt < 4; mt++) acc[mt] = (f32x4){0.f, 0.f, 0.f, 0.f};

            if (layer == 0) {
                // segment 1: x_p, kt = 0..7
                if (use_xbf) {
                    const unsigned short* xp = xbf + (size_t)p * BB * EE;
                    #pragma unroll 4
                    for (int kt = 0; kt < 8; kt++) {
                        short8 bfrag = *(const short8*)&wlds[n16 * stride + kt * 32 + q8];
                        #pragma unroll
                        for (int mt = 0; mt < 4; mt++) {
                            short8 af = *(const short8*)(xp + (size_t)mrow[mt] * EE + kt * 32 + q8);
                            acc[mt] = __builtin_amdgcn_mfma_f32_16x16x32_bf16(af, bfrag, acc[mt], 0, 0, 0);
                        }
                    }
                } else {
                    #pragma unroll 2
                    for (int kt = 0; kt < 8; kt++) {
                        short8 bfrag = *(const short8*)&wlds[n16 * stride + kt * 32 + q8];
                        #pragma unroll
                        for (int mt = 0; mt < 4; mt++) {
                            const float* e = emb + (size_t)tokl[mrow[mt]] * EE + kt * 32 + q8;
                            float4 f0 = *(const float4*)e;
                            float4 f1 = *(const float4*)(e + 4);
                            U8 u;
                            u.s[0] = f2bf(f0.x); u.s[1] = f2bf(f0.y); u.s[2] = f2bf(f0.z); u.s[3] = f2bf(f0.w);
                            u.s[4] = f2bf(f1.x); u.s[5] = f2bf(f1.y); u.s[6] = f2bf(f1.z); u.s[7] = f2bf(f1.w);
                            acc[mt] = __builtin_amdgcn_mfma_f32_16x16x32_bf16(u.v, bfrag, acc[mt], 0, 0, 0);
                        }
                    }
                }
                // segment 2: h0(p), kt = 8..23
                #pragma unroll 4
                for (int kt = 8; kt < 24; kt++) {
                    short8 bfrag = *(const short8*)&wlds[n16 * stride + kt * 32 + q8];
                    #pragma unroll
                    for (int mt = 0; mt < 4; mt++) {
                        short8 af = *(const short8*)(h0r + (size_t)mrow[mt] * UU + (kt - 8) * 32 + q8);
                        acc[mt] = __builtin_amdgcn_mfma_f32_16x16x32_bf16(af, bfrag, acc[mt], 0, 0, 0);
                    }
                }
            } else {
                // segment 1: h0(p), kt = 0..15
                #pragma unroll 4
                for (int kt = 0; kt < 16; kt++) {
                    short8 bfrag = *(const short8*)&wlds[n16 * stride + kt * 32 + q8];
                    #pragma unroll
                    for (int mt = 0; mt < 4; mt++) {
                        short8 af = *(const short8*)(h0r + (size_t)mrow[mt] * UU + kt * 32 + q8);
                        acc[mt] = __builtin_amdgcn_mfma_f32_16x16x32_bf16(af, bfrag, acc[mt], 0, 0, 0);
                    }
                }
                // segment 2: h1(p-1), kt = 16..31
                #pragma unroll 4
                for (int kt = 16; kt < 32; kt++) {
                    short8 bfrag = *(const short8*)&wlds[n16 * stride + kt * 32 + q8];
                    #pragma unroll
                    for (int mt = 0; mt < 4; mt++) {
                        short8 af = *(const short8*)(h1r + (size_t)mrow[mt] * UU + (kt - 16) * 32 + q8);
                        acc[mt] = __builtin_amdgcn_mfma_f32_16x16x32_bf16(af, bfrag, acc[mt], 0, 0, 0);
                    }
                }
            }

            // stage z tile to LDS: D layout col=lane&15, row=(lane>>4)*4+r
            #pragma unroll
            for (int mt = 0; mt < 4; mt++)
                #pragma unroll
                for (int r = 0; r < 4; r++)
                    zbuf[(w * 64 + mt * 16 + q * 4 + r) * 17 + n16] = acc[mt][r];
            __syncthreads();

            // gating: thread tid owns batch row b=tid, u = u0 + j (j=0..3)
            ushort4 hv;
            unsigned short hh[4];
            #pragma unroll
            for (int j = 0; j < 4; j++) {
                float zi = zbuf[tid * 17 + 0 * 4 + j] + bias_r[0][j];
                float zf = zbuf[tid * 17 + 1 * 4 + j] + bias_r[1][j];
                float zg = zbuf[tid * 17 + 2 * 4 + j] + bias_r[2][j];
                float zo = zbuf[tid * 17 + 3 * 4 + j] + bias_r[3][j];
                float cn = sigf(zf) * cstate[j] + sigf(zi) * tanhf(zg);
                cstate[j] = cn;
                hh[j] = (unsigned short)f2bf(sigf(zo) * tanhf(cn));
            }
            hv.x = hh[0]; hv.y = hh[1]; hv.z = hh[2]; hv.w = hh[3];
            *(ushort4*)(hw + (size_t)tid * UU + u0) = hv;
            __syncthreads();  // zbuf safe before next phase (belt & braces, block-uniform)
        }
        grid.sync();
    }
}

// ---------- final dense: out[b] = sigmoid(h1 . Wd + bd) ----------
__global__ __launch_bounds__(64) void dense_out(
    const unsigned short* __restrict__ h, const float* __restrict__ Wd,
    const float* __restrict__ bd, float* __restrict__ out)
{
    int b = blockIdx.x;
    int lane = threadIdx.x;
    float s = 0.f;
    #pragma unroll
    for (int k = lane; k < UU; k += 64) s += bf2f(h[(size_t)b * UU + k]) * Wd[k];
    #pragma unroll
    for (int off = 32; off > 0; off >>= 1) s += __shfl_down(s, off);
    if (lane == 0) out[b] = sigf(s + bd[0]);
}

extern "C" void kernel_launch(void* const* d_in, const int* in_sizes, int n_in,
                              void* d_out, int out_size, void* d_ws, size_t ws_size,
                              hipStream_t stream) {
    const int*   tokens = (const int*)  d_in[0];
    const float* emb    = (const float*)d_in[1];
    const float* W0     = (const float*)d_in[2];
    const float* U0     = (const float*)d_in[3];
    const float* b0     = (const float*)d_in[4];
    const float* W1     = (const float*)d_in[5];
    const float* U1     = (const float*)d_in[6];
    const float* b1     = (const float*)d_in[7];
    const float* Wd     = (const float*)d_in[8];
    const float* bd     = (const float*)d_in[9];
    float* out = (float*)d_out;

    // ws layout (bytes)
    const size_t oWt0 = 0;
    const size_t oWt1 = (size_t)G4 * 768 * 2;               // 3,145,728
    const size_t oX   = oWt1 + (size_t)G4 * 1024 * 2;       // 7,340,032
    const size_t xBytes = (size_t)TT * BB * EE * 2;         // 33,554,432
    const size_t needFull = oX + xBytes + 2 * 1048576;
    int use_xbf = (ws_size >= needFull) ? 1 : 0;
    const size_t oH0 = use_xbf ? (oX + xBytes) : oX;
    const size_t oH1 = oH0 + (size_t)2 * BB * UU * 2;

    unsigned short* Wt0p = (unsigned short*)((char*)d_ws + oWt0);
    unsigned short* Wt1p = (unsigned short*)((char*)d_ws + oWt1);
    unsigned short* xbfp = (unsigned short*)((char*)d_ws + oX);
    unsigned short* h0p  = (unsigned short*)((char*)d_ws + oH0);
    unsigned short* h1p  = (unsigned short*)((char*)d_ws + oH1);

    // zero h state (both parities, both layers)
    hipMemsetAsync(h0p, 0, (size_t)4 * BB * UU * 2, stream);

    // weight transpose+convert
    wtrans<<<dim3(G4 / 32,  EE / 32), dim3(32, 8), 0, stream>>>(W0, EE,  Wt0p, 768, 0);
    wtrans<<<dim3(G4 / 32,  UU / 32), dim3(32, 8), 0, stream>>>(U0, UU,  Wt0p, 768, 256);
    wtrans<<<dim3(G4 / 32,  UU / 32), dim3(32, 8), 0, stream>>>(W1, UU,  Wt1p, 1024, 0);
    wtrans<<<dim3(G4 / 32,  UU / 32), dim3(32, 8), 0, stream>>>(U1, UU,  Wt1p, 1024, 512);

    if (use_xbf)
        xgather<<<dim3(BB * TT), dim3(64), 0, stream>>>(tokens, emb, xbfp);

    // persistent pipelined LSTM (cooperative: one grid sync per step)
    {
        void* args[] = {(void*)&Wt0p, (void*)&Wt1p, (void*)&xbfp,
                        (void*)&tokens, (void*)&emb, (void*)&b0, (void*)&b1,
                        (void*)&h0p, (void*)&h1p, (void*)&use_xbf};
        hipLaunchCooperativeKernel((const void*)rnn_persist, dim3(256), dim3(256),
                                   args, 0, stream);
    }

    dense_out<<<dim3(BB), dim3(64), 0, stream>>>(h1p, Wd, bd, out);
}

// Round 3
// 6606.544 us; speedup vs baseline: 3.5482x; 1.9694x over previous
//
#include <hip/hip_runtime.h>
#include <hip/hip_bf16.h>
#include <hip/hip_cooperative_groups.h>
#include <math.h>

#define VB 50000
#define EE 256
#define UU 512
#define BB 256
#define TT 256
#define G4 2048

typedef __attribute__((ext_vector_type(8))) short short8;
typedef __attribute__((ext_vector_type(4))) float f32x4;

__device__ __forceinline__ float sigf(float x){ return 1.0f/(1.0f+expf(-x)); }
__device__ __forceinline__ unsigned short f2bf(float f){
    __hip_bfloat16 h = __float2bfloat16(f);   // RNE
    unsigned short s; __builtin_memcpy(&s,&h,2); return s;
}
__device__ __forceinline__ float bf2f(unsigned short u){
    unsigned int x = ((unsigned int)u)<<16; float f; __builtin_memcpy(&f,&x,4); return f;
}

// 16-byte device-coherent load as 2x8B agent-scope relaxed atomics (sc0 sc1:
// bypasses stale per-CU L1 / per-XCD L2, served from the coherent point).
struct AF { unsigned long long a, b; };
__device__ __forceinline__ AF cload16(const unsigned short* p){
    const unsigned long long* q = (const unsigned long long*)p;
    AF r;
    r.a = __hip_atomic_load(q,   __ATOMIC_RELAXED, __HIP_MEMORY_SCOPE_AGENT);
    r.b = __hip_atomic_load(q+1, __ATOMIC_RELAXED, __HIP_MEMORY_SCOPE_AGENT);
    return r;
}
__device__ __forceinline__ short8 af2v(AF x){
    union { unsigned long long u[2]; short8 v; } c; c.u[0]=x.a; c.u[1]=x.b; return c.v;
}

// ---------- pre-pass: transpose+convert W [rows][2048] fp32 -> out[c][koff+k] bf16 ----------
__global__ __launch_bounds__(256) void wtrans(const float* __restrict__ in, int rows,
                                              unsigned short* __restrict__ out,
                                              int Kout, int koff) {
    __shared__ float tl[32][33];
    int tx = threadIdx.x, ty = threadIdx.y;
    int c0 = blockIdx.x * 32, k0 = blockIdx.y * 32;
    #pragma unroll
    for (int i = 0; i < 4; i++)
        tl[ty + i * 8][tx] = in[(size_t)(k0 + ty + i * 8) * G4 + c0 + tx];
    __syncthreads();
    #pragma unroll
    for (int i = 0; i < 4; i++)
        out[(size_t)(c0 + ty + i * 8) * Kout + koff + k0 + tx] = f2bf(tl[tx][ty + i * 8]);
}

// ---------- pre-pass: gather embeddings -> xbf[t][b][k] bf16 ----------
__global__ __launch_bounds__(64) void xgather(const int* __restrict__ tokens,
                                              const float* __restrict__ emb,
                                              unsigned short* __restrict__ xbf) {
    int flat = blockIdx.x;
    int b = flat & 255, t = flat >> 8;
    int tok = tokens[b * TT + t];
    float4 v = ((const float4*)(emb + (size_t)tok * EE))[threadIdx.x];
    ushort4 o;
    o.x = f2bf(v.x); o.y = f2bf(v.y); o.z = f2bf(v.z); o.w = f2bf(v.w);
    ((ushort4*)(xbf + ((size_t)t * BB + b) * EE))[threadIdx.x] = o;
}

// ---------- persistent 2-layer LSTM ----------
// 4 groups x 64 blocks. Group g owns batch rows [g*64, g*64+64).
// Within a group: blocks 0..31 = layer0 (K=768: x|h0), 32..63 = layer1 (K=1024: h0|h1).
// Each block owns 16 u's (64 z-cols: gate*512+u0+0..15). Wave w owns m-tile rows w*16..w*16+15,
// loops all 4 gate n-tiles -> lane holds z_i,f,g,o for its (row,u) in registers; c-state in
// registers for all 256 steps. Weights stream from L2 (never invalidated: no acquire fences).
// h0/h1 cross-block traffic via agent-scope relaxed atomics; per-group monotonic spin barrier.
__global__ __launch_bounds__(256, 1) void rnn_persist(
    const unsigned short* __restrict__ Wt0,   // [2048][768]  bf16, col-major-K
    const unsigned short* __restrict__ Wt1,   // [2048][1024]
    const unsigned short* __restrict__ xbf,   // [256][256][256] bf16 (or unused)
    const int* __restrict__ tokens, const float* __restrict__ emb,
    const float* __restrict__ b0v, const float* __restrict__ b1v,
    unsigned short* __restrict__ h0buf,       // [2][256][512] bf16
    unsigned short* __restrict__ h1buf,       // [2][256][512] bf16
    unsigned int* __restrict__ bars,          // 4 counters, 256B apart
    int use_xbf)
{
    __shared__ int tokl[64];

    const int tid   = threadIdx.x;
    const int bid   = blockIdx.x;
    const int g     = bid >> 6;
    const int local = bid & 63;
    const int layer = local >> 5;
    const int u0    = (local & 31) * 16;
    const int row0  = g * 64;
    const int K     = layer ? 1024 : 768;
    const unsigned short* Wt = layer ? Wt1 : Wt0;
    const float* bR = layer ? b1v : b0v;

    const int lane = tid & 63;
    const int w    = tid >> 6;     // wave 0..3 owns rows row0+w*16 .. +15
    const int n16  = lane & 15;
    const int q    = lane >> 4;
    const int q8   = q * 8;

    const int myrow = row0 + w * 16 + n16;   // row this lane loads for A-fragments

    // B-fragment base pointers (per gate) — fixed for all phases
    const unsigned short* bp[4];
    #pragma unroll
    for (int gate = 0; gate < 4; gate++)
        bp[gate] = Wt + (size_t)(gate * UU + u0 + n16) * K + q8;

    float gb[4];
    #pragma unroll
    for (int gate = 0; gate < 4; gate++) gb[gate] = bR[gate * UU + u0 + n16];

    float cst[4] = {0.f, 0.f, 0.f, 0.f};   // c-state for rows row0+w*16+q*4+r, u=u0+n16

    unsigned int* bar = bars + (size_t)g * 64;
    const size_t HS = (size_t)BB * UU;

    for (int p = 0; p <= TT; p++) {
        const bool active = layer ? (p >= 1) : (p < TT);

        if (layer == 0 && !use_xbf && p < TT) {
            if (tid < 64) tokl[tid] = tokens[(size_t)(row0 + tid) * TT + p];
            __syncthreads();
        }

        if (active) {
            const unsigned short* h0r = h0buf + (size_t)(p & 1) * HS;
            const unsigned short* h1r = h1buf + (size_t)((p + 1) & 1) * HS;  // (p-1)&1
            unsigned short* hw = layer ? (h1buf + (size_t)(p & 1) * HS)
                                       : (h0buf + (size_t)((p + 1) & 1) * HS);

            f32x4 acc[4];
            #pragma unroll
            for (int gate = 0; gate < 4; gate++) acc[gate] = (f32x4){0.f, 0.f, 0.f, 0.f};

            if (layer) {
                // K-loop: kt 0..15 from h0(p), kt 16..31 from h1(p-1); 2-stage A prefetch
                const unsigned short* a0 = h0r + (size_t)myrow * UU + q8;
                const unsigned short* a1 = h1r + (size_t)myrow * UU + q8;
                AF abuf[2][8];
                #pragma unroll
                for (int i = 0; i < 8; i++) abuf[0][i] = cload16(a0 + i * 32);
                #pragma unroll
                for (int oct = 0; oct < 4; oct++) {
                    const int cur = oct & 1, nxt = cur ^ 1;
                    if (oct < 3) {
                        #pragma unroll
                        for (int i = 0; i < 8; i++) {
                            int kt = (oct + 1) * 8 + i;
                            const unsigned short* ap = (kt < 16) ? (a0 + kt * 32)
                                                                 : (a1 + (kt - 16) * 32);
                            abuf[nxt][i] = cload16(ap);
                        }
                    }
                    #pragma unroll
                    for (int i = 0; i < 8; i++) {
                        int kt = oct * 8 + i;
                        short8 av = af2v(abuf[cur][i]);
                        #pragma unroll
                        for (int gate = 0; gate < 4; gate++) {
                            short8 bv = *(const short8*)(bp[gate] + kt * 32);
                            acc[gate] = __builtin_amdgcn_mfma_f32_16x16x32_bf16(av, bv, acc[gate], 0, 0, 0);
                        }
                    }
                }
            } else {
                // L0: kt 0..7 = x_p (normal cached loads), kt 8..23 = h0(p) (coherent)
                const unsigned short* ah = h0r + (size_t)myrow * UU + q8;
                AF abuf[2][8];
                #pragma unroll
                for (int i = 0; i < 8; i++) abuf[0][i] = cload16(ah + i * 32);   // kt 8..15, issued early

                if (use_xbf) {
                    const unsigned short* xp = xbf + ((size_t)p * BB + myrow) * EE + q8;
                    #pragma unroll
                    for (int kt = 0; kt < 8; kt++) {
                        short8 av = *(const short8*)(xp + kt * 32);
                        #pragma unroll
                        for (int gate = 0; gate < 4; gate++) {
                            short8 bv = *(const short8*)(bp[gate] + kt * 32);
                            acc[gate] = __builtin_amdgcn_mfma_f32_16x16x32_bf16(av, bv, acc[gate], 0, 0, 0);
                        }
                    }
                } else {
                    const float* ep = emb + (size_t)tokl[w * 16 + n16] * EE + q8;
                    #pragma unroll
                    for (int kt = 0; kt < 8; kt++) {
                        float4 f0 = *(const float4*)(ep + kt * 32);
                        float4 f1 = *(const float4*)(ep + kt * 32 + 4);
                        union { unsigned short s[8]; short8 v; } u;
                        u.s[0]=f2bf(f0.x); u.s[1]=f2bf(f0.y); u.s[2]=f2bf(f0.z); u.s[3]=f2bf(f0.w);
                        u.s[4]=f2bf(f1.x); u.s[5]=f2bf(f1.y); u.s[6]=f2bf(f1.z); u.s[7]=f2bf(f1.w);
                        #pragma unroll
                        for (int gate = 0; gate < 4; gate++) {
                            short8 bv = *(const short8*)(bp[gate] + kt * 32);
                            acc[gate] = __builtin_amdgcn_mfma_f32_16x16x32_bf16(u.v, bv, acc[gate], 0, 0, 0);
                        }
                    }
                }
                #pragma unroll
                for (int i = 0; i < 8; i++) abuf[1][i] = cload16(ah + (8 + i) * 32); // kt 16..23
                #pragma unroll
                for (int half = 0; half < 2; half++) {
                    #pragma unroll
                    for (int i = 0; i < 8; i++) {
                        int kt = 8 + half * 8 + i;
                        short8 av = af2v(abuf[half][i]);
                        #pragma unroll
                        for (int gate = 0; gate < 4; gate++) {
                            short8 bv = *(const short8*)(bp[gate] + kt * 32);
                            acc[gate] = __builtin_amdgcn_mfma_f32_16x16x32_bf16(av, bv, acc[gate], 0, 0, 0);
                        }
                    }
                }
            }

            // In-register gating. D layout: col=lane&15 (=n16 -> u), row=q*4+r (batch row in m-tile)
            #pragma unroll
            for (int r = 0; r < 4; r++) {
                float zi = acc[0][r] + gb[0];
                float zf = acc[1][r] + gb[1];
                float zg = acc[2][r] + gb[2];
                float zo = acc[3][r] + gb[3];
                float cn = sigf(zf) * cst[r] + sigf(zi) * tanhf(zg);
                cst[r] = cn;
                unsigned short hv = f2bf(sigf(zo) * tanhf(cn));
                int row = row0 + w * 16 + q * 4 + r;
                __hip_atomic_store(hw + (size_t)row * UU + u0 + n16, hv,
                                   __ATOMIC_RELAXED, __HIP_MEMORY_SCOPE_AGENT);
            }
        }

        // ---- per-group barrier: no cache flushes, monotonic counter ----
        if (p < TT) {
            asm volatile("s_waitcnt vmcnt(0)" ::: "memory");  // our coherent stores ack'd
            __syncthreads();                                   // all waves drained (compiler adds vmcnt(0))
            if (tid == 0) {
                __hip_atomic_fetch_add(bar, 1u, __ATOMIC_RELAXED, __HIP_MEMORY_SCOPE_AGENT);
                unsigned int tgt = 64u * (unsigned int)(p + 1);
                while (__hip_atomic_load(bar, __ATOMIC_RELAXED, __HIP_MEMORY_SCOPE_AGENT) < tgt) {}
            }
            __syncthreads();
        }
    }
}

// ---------- final dense: out[b] = sigmoid(h1 . Wd + bd) ----------
__global__ __launch_bounds__(64) void dense_out(
    const unsigned short* __restrict__ h, const float* __restrict__ Wd,
    const float* __restrict__ bd, float* __restrict__ out)
{
    int b = blockIdx.x;
    int lane = threadIdx.x;
    float s = 0.f;
    #pragma unroll
    for (int k = lane; k < UU; k += 64) s += bf2f(h[(size_t)b * UU + k]) * Wd[k];
    #pragma unroll
    for (int off = 32; off > 0; off >>= 1) s += __shfl_down(s, off);
    if (lane == 0) out[b] = sigf(s + bd[0]);
}

extern "C" void kernel_launch(void* const* d_in, const int* in_sizes, int n_in,
                              void* d_out, int out_size, void* d_ws, size_t ws_size,
                              hipStream_t stream) {
    const int*   tokens = (const int*)  d_in[0];
    const float* emb    = (const float*)d_in[1];
    const float* W0     = (const float*)d_in[2];
    const float* U0     = (const float*)d_in[3];
    const float* b0     = (const float*)d_in[4];
    const float* W1     = (const float*)d_in[5];
    const float* U1     = (const float*)d_in[6];
    const float* b1     = (const float*)d_in[7];
    const float* Wd     = (const float*)d_in[8];
    const float* bd     = (const float*)d_in[9];
    float* out = (float*)d_out;

    // ws layout (bytes):
    // [Wt0 3MB][Wt1 4MB][h0 2x256KB][h1 2x256KB][bars 4KB][xbf 32MB]
    const size_t oWt0 = 0;
    const size_t oWt1 = (size_t)G4 * 768 * 2;                 // 3,145,728
    const size_t oH0  = oWt1 + (size_t)G4 * 1024 * 2;         // 7,340,032
    const size_t oH1  = oH0 + (size_t)2 * BB * UU * 2;        // +524,288
    const size_t oBar = oH1 + (size_t)2 * BB * UU * 2;        // +524,288
    const size_t oX   = oBar + 4096;
    const size_t needFull = oX + (size_t)TT * BB * EE * 2;    // ~41.9 MB
    int use_xbf = (ws_size >= needFull) ? 1 : 0;

    unsigned short* Wt0p = (unsigned short*)((char*)d_ws + oWt0);
    unsigned short* Wt1p = (unsigned short*)((char*)d_ws + oWt1);
    unsigned short* h0p  = (unsigned short*)((char*)d_ws + oH0);
    unsigned short* h1p  = (unsigned short*)((char*)d_ws + oH1);
    unsigned int*   barp = (unsigned int*)  ((char*)d_ws + oBar);
    unsigned short* xbfp = (unsigned short*)((char*)d_ws + oX);

    // zero h state (both layers, both parities) + barrier counters, one contiguous memset
    hipMemsetAsync((char*)d_ws + oH0, 0, (oBar + 4096) - oH0, stream);

    // weight transpose+convert (runs while memset is queued; same stream = ordered)
    wtrans<<<dim3(G4 / 32, EE / 32), dim3(32, 8), 0, stream>>>(W0, EE, Wt0p, 768, 0);
    wtrans<<<dim3(G4 / 32, UU / 32), dim3(32, 8), 0, stream>>>(U0, UU, Wt0p, 768, 256);
    wtrans<<<dim3(G4 / 32, UU / 32), dim3(32, 8), 0, stream>>>(W1, UU, Wt1p, 1024, 0);
    wtrans<<<dim3(G4 / 32, UU / 32), dim3(32, 8), 0, stream>>>(U1, UU, Wt1p, 1024, 512);

    if (use_xbf)
        xgather<<<dim3(BB * TT), dim3(64), 0, stream>>>(tokens, emb, xbfp);

    {
        void* args[] = {(void*)&Wt0p, (void*)&Wt1p, (void*)&xbfp,
                        (void*)&tokens, (void*)&emb, (void*)&b0, (void*)&b1,
                        (void*)&h0p, (void*)&h1p, (void*)&barp, (void*)&use_xbf};
        hipLaunchCooperativeKernel((const void*)rnn_persist, dim3(256), dim3(256),
                                   args, 0, stream);
    }

    dense_out<<<dim3(BB), dim3(64), 0, stream>>>(h1p, Wd, bd, out);
}

// Round 4
// 3086.062 us; speedup vs baseline: 7.5958x; 2.1408x over previous
//
#include <hip/hip_runtime.h>
#include <hip/hip_bf16.h>
#include <math.h>

#define VB 50000
#define EE 256
#define UU 512
#define BB 256
#define TT 256
#define G4 2048

typedef __attribute__((ext_vector_type(8))) short short8;
typedef __attribute__((ext_vector_type(4))) float f32x4;

__device__ __forceinline__ float sigf(float x){ return 1.0f/(1.0f+expf(-x)); }
__device__ __forceinline__ unsigned short f2bf(float f){
    __hip_bfloat16 h = __float2bfloat16(f);   // RNE
    unsigned short s; __builtin_memcpy(&s,&h,2); return s;
}
__device__ __forceinline__ float bf2f(unsigned short u){
    unsigned int x = ((unsigned int)u)<<16; float f; __builtin_memcpy(&f,&x,4); return f;
}

// 16-byte device-coherent load as 2x8B agent-scope relaxed atomics (sc0 sc1:
// bypass stale per-CU L1 / per-XCD L2; served at the coherent point).
struct AF { unsigned long long a, b; };
__device__ __forceinline__ AF cload16(const unsigned short* p){
    const unsigned long long* q = (const unsigned long long*)p;
    AF r;
    r.a = __hip_atomic_load(q,   __ATOMIC_RELAXED, __HIP_MEMORY_SCOPE_AGENT);
    r.b = __hip_atomic_load(q+1, __ATOMIC_RELAXED, __HIP_MEMORY_SCOPE_AGENT);
    return r;
}
__device__ __forceinline__ short8 af2v(AF x){
    union { unsigned long long u[2]; short8 v; } c; c.u[0]=x.a; c.u[1]=x.b; return c.v;
}

// ---------- pre-pass: transpose+convert W [rows][2048] fp32 -> out[c][koff+k] bf16 ----------
__global__ __launch_bounds__(256) void wtrans(const float* __restrict__ in, int rows,
                                              unsigned short* __restrict__ out,
                                              int Kout, int koff) {
    __shared__ float tl[32][33];
    int tx = threadIdx.x, ty = threadIdx.y;
    int c0 = blockIdx.x * 32, k0 = blockIdx.y * 32;
    #pragma unroll
    for (int i = 0; i < 4; i++)
        tl[ty + i * 8][tx] = in[(size_t)(k0 + ty + i * 8) * G4 + c0 + tx];
    __syncthreads();
    #pragma unroll
    for (int i = 0; i < 4; i++)
        out[(size_t)(c0 + ty + i * 8) * Kout + koff + k0 + tx] = f2bf(tl[tx][ty + i * 8]);
}

// ---------- pre-pass: gather embeddings -> xbf[t][b][k] bf16 ----------
__global__ __launch_bounds__(64) void xgather(const int* __restrict__ tokens,
                                              const float* __restrict__ emb,
                                              unsigned short* __restrict__ xbf) {
    int flat = blockIdx.x;
    int b = flat & 255, t = flat >> 8;
    int tok = tokens[b * TT + t];
    float4 v = ((const float4*)(emb + (size_t)tok * EE))[threadIdx.x];
    ushort4 o;
    o.x = f2bf(v.x); o.y = f2bf(v.y); o.z = f2bf(v.z); o.w = f2bf(v.w);
    ((ushort4*)(xbf + ((size_t)t * BB + b) * EE))[threadIdx.x] = o;
}

// ---------- persistent 2-layer LSTM ----------
// 4 groups x 64 blocks; group g owns batch rows [g*64, g*64+64).
// local 0..31 = layer0 (K=768: x|h0), 32..63 = layer1 (K=1024: h0|h1); 16 u's / block.
// Weights LDS-resident (frag-contiguous). c-state in registers. h via agent-scope
// relaxed atomics. Barrier: per-block arrival slots + leader ballot + go broadcast.
__global__ __launch_bounds__(256, 1) void rnn_persist(
    const unsigned short* __restrict__ Wt0,   // [2048][768]  bf16 [col][k]
    const unsigned short* __restrict__ Wt1,   // [2048][1024]
    const unsigned short* __restrict__ xbf,   // [256][256][256] bf16 (or unused)
    const int* __restrict__ tokens, const float* __restrict__ emb,
    const float* __restrict__ b0v, const float* __restrict__ b1v,
    unsigned short* __restrict__ h0buf,       // [2][256][512] bf16
    unsigned short* __restrict__ h1buf,       // [2][256][512] bf16
    unsigned int* __restrict__ bars,          // per group: 64 arrival slots + go
    int use_xbf)
{
    extern __shared__ char smem[];
    unsigned short* wl  = (unsigned short*)smem;               // frag-ordered weights (<=128KB)
    unsigned short* hst = (unsigned short*)(smem + 131072);    // 64x16 h staging (2KB)
    int*            tokl = (int*)(smem + 131072 + 2048);       // 64 ints

    const int tid   = threadIdx.x;
    const int bid   = blockIdx.x;
    const int g     = bid >> 6;
    const int local = bid & 63;
    const int layer = local >> 5;
    const int u0    = (local & 31) * 16;
    const int row0  = g * 64;
    const int K     = layer ? 1024 : 768;
    const int KT    = K / 32;                  // 32 or 24 k-tiles
    const unsigned short* Wt = layer ? Wt1 : Wt0;
    const float* bR = layer ? b1v : b0v;

    // ---- fill LDS weights, frag-contiguous: chunk i = ((gate*KT+kt)*64 + (n*4+q)) ----
    const int nch = 4 * KT * 64;
    for (int i = tid; i < nch; i += 256) {
        int q  = i & 3;
        int n  = (i >> 2) & 15;
        int t2 = i >> 6;
        int kt = t2 % KT, gate = t2 / KT;
        const unsigned short* src = Wt + (size_t)(gate * UU + u0 + n) * K + kt * 32 + q * 8;
        *(short8*)(wl + (size_t)i * 8) = *(const short8*)src;
    }

    float gb[4];
    #pragma unroll
    for (int gate = 0; gate < 4; gate++) gb[gate] = bR[gate * UU + u0 + (tid & 15)];
    float cst[4] = {0.f, 0.f, 0.f, 0.f};

    const int lane = tid & 63;
    const int w    = tid >> 6;
    const int n16  = lane & 15;
    const int q    = lane >> 4;
    const int q8   = q * 8;
    const int myrow = row0 + w * 16 + n16;
    const unsigned short* wlane = wl + (n16 * 4 + q) * 8;   // + (gate*KT+kt)*512 shorts

    unsigned int* arr = bars + (size_t)g * 128;
    unsigned int* go  = arr + 64;
    const size_t HS = (size_t)BB * UU;

    __syncthreads();   // wl ready

    for (int p = 0; p <= TT; p++) {
        const bool active = layer ? (p >= 1) : (p < TT);

        if (layer == 0 && !use_xbf && p < TT) {
            if (tid < 64) tokl[tid] = tokens[(size_t)(row0 + tid) * TT + p];
            __syncthreads();
        }

        if (active) {
            const unsigned short* h0r = h0buf + (size_t)(p & 1) * HS;
            const unsigned short* h1r = h1buf + (size_t)((p + 1) & 1) * HS;  // (p-1)&1
            unsigned short* hw = layer ? (h1buf + (size_t)(p & 1) * HS)
                                       : (h0buf + (size_t)((p + 1) & 1) * HS);

            f32x4 acc[4];
            #pragma unroll
            for (int gate = 0; gate < 4; gate++) acc[gate] = (f32x4){0.f, 0.f, 0.f, 0.f};

            if (layer) {
                const unsigned short* a0 = h0r + (size_t)myrow * UU + q8;
                const unsigned short* a1 = h1r + (size_t)myrow * UU + q8;
                AF ab[2][16];
                #pragma unroll
                for (int i = 0; i < 16; i++) ab[0][i] = cload16(a0 + i * 32);
                #pragma unroll
                for (int i = 0; i < 16; i++) ab[1][i] = cload16(a1 + i * 32);
                #pragma unroll
                for (int half = 0; half < 2; half++) {
                    #pragma unroll
                    for (int i = 0; i < 16; i++) {
                        int kt = half * 16 + i;
                        short8 av = af2v(ab[half][i]);
                        #pragma unroll
                        for (int gate = 0; gate < 4; gate++) {
                            short8 bv = *(const short8*)(wlane + (size_t)(gate * KT + kt) * 512);
                            acc[gate] = __builtin_amdgcn_mfma_f32_16x16x32_bf16(av, bv, acc[gate], 0, 0, 0);
                        }
                    }
                }
            } else {
                const unsigned short* ah = h0r + (size_t)myrow * UU + q8;
                AF ab[16];
                #pragma unroll
                for (int i = 0; i < 16; i++) ab[i] = cload16(ah + i * 32);   // kt 8..23

                if (use_xbf) {
                    const unsigned short* xp = xbf + ((size_t)p * BB + myrow) * EE + q8;
                    #pragma unroll
                    for (int kt = 0; kt < 8; kt++) {
                        short8 av = *(const short8*)(xp + kt * 32);
                        #pragma unroll
                        for (int gate = 0; gate < 4; gate++) {
                            short8 bv = *(const short8*)(wlane + (size_t)(gate * KT + kt) * 512);
                            acc[gate] = __builtin_amdgcn_mfma_f32_16x16x32_bf16(av, bv, acc[gate], 0, 0, 0);
                        }
                    }
                } else {
                    const float* ep = emb + (size_t)tokl[w * 16 + n16] * EE + q8;
                    #pragma unroll
                    for (int kt = 0; kt < 8; kt++) {
                        float4 f0 = *(const float4*)(ep + kt * 32);
                        float4 f1 = *(const float4*)(ep + kt * 32 + 4);
                        union { unsigned short s[8]; short8 v; } u;
                        u.s[0]=f2bf(f0.x); u.s[1]=f2bf(f0.y); u.s[2]=f2bf(f0.z); u.s[3]=f2bf(f0.w);
                        u.s[4]=f2bf(f1.x); u.s[5]=f2bf(f1.y); u.s[6]=f2bf(f1.z); u.s[7]=f2bf(f1.w);
                        #pragma unroll
                        for (int gate = 0; gate < 4; gate++) {
                            short8 bv = *(const short8*)(wlane + (size_t)(gate * KT + kt) * 512);
                            acc[gate] = __builtin_amdgcn_mfma_f32_16x16x32_bf16(u.v, bv, acc[gate], 0, 0, 0);
                        }
                    }
                }
                #pragma unroll
                for (int i = 0; i < 16; i++) {
                    int kt = 8 + i;
                    short8 av = af2v(ab[i]);
                    #pragma unroll
                    for (int gate = 0; gate < 4; gate++) {
                        short8 bv = *(const short8*)(wlane + (size_t)(gate * KT + kt) * 512);
                        acc[gate] = __builtin_amdgcn_mfma_f32_16x16x32_bf16(av, bv, acc[gate], 0, 0, 0);
                    }
                }
            }

            // gating (D layout: col=n16 -> u, row=q*4+r); stage h to LDS
            #pragma unroll
            for (int r = 0; r < 4; r++) {
                float zi = acc[0][r] + gb[0];
                float zf = acc[1][r] + gb[1];
                float zg = acc[2][r] + gb[2];
                float zo = acc[3][r] + gb[3];
                float cn = sigf(zf) * cst[r] + sigf(zi) * tanhf(zg);
                cst[r] = cn;
                hst[(w * 16 + q * 4 + r) * 16 + n16] = f2bf(sigf(zo) * tanhf(cn));
            }
            __syncthreads();   // block-uniform (active is block-uniform)
            // coalesced coherent store: 128 threads x 16B
            if (tid < 128) {
                int row = tid >> 1, half = tid & 1;
                const unsigned long long* s = (const unsigned long long*)(hst + row * 16 + half * 8);
                unsigned long long* dp = (unsigned long long*)(hw + (size_t)(row0 + row) * UU + u0 + half * 8);
                __hip_atomic_store(dp,     s[0], __ATOMIC_RELAXED, __HIP_MEMORY_SCOPE_AGENT);
                __hip_atomic_store(dp + 1, s[1], __ATOMIC_RELAXED, __HIP_MEMORY_SCOPE_AGENT);
            }
        }

        // ---- barrier: arrival slots + leader ballot + go broadcast ----
        if (p < TT) {
            asm volatile("s_waitcnt vmcnt(0)" ::: "memory");
            __syncthreads();
            const unsigned int tgt = (unsigned int)(p + 1);
            if (tid == 0)
                __hip_atomic_store(&arr[local], tgt, __ATOMIC_RELAXED, __HIP_MEMORY_SCOPE_AGENT);
            if (local == 0) {
                if (tid < 64) {
                    for (;;) {
                        unsigned int a = __hip_atomic_load(&arr[tid], __ATOMIC_RELAXED, __HIP_MEMORY_SCOPE_AGENT);
                        if (__ballot(a < tgt) == 0ULL) break;
                        __builtin_amdgcn_s_sleep(1);
                    }
                    if (tid == 0)
                        __hip_atomic_store(go, tgt, __ATOMIC_RELAXED, __HIP_MEMORY_SCOPE_AGENT);
                }
            } else if (tid == 0) {
                while (__hip_atomic_load(go, __ATOMIC_RELAXED, __HIP_MEMORY_SCOPE_AGENT) < tgt)
                    __builtin_amdgcn_s_sleep(1);
            }
            __syncthreads();
        }
    }
}

// ---------- final dense: out[b] = sigmoid(h1 . Wd + bd) ----------
__global__ __launch_bounds__(64) void dense_out(
    const unsigned short* __restrict__ h, const float* __restrict__ Wd,
    const float* __restrict__ bd, float* __restrict__ out)
{
    int b = blockIdx.x;
    int lane = threadIdx.x;
    float s = 0.f;
    #pragma unroll
    for (int k = lane; k < UU; k += 64) s += bf2f(h[(size_t)b * UU + k]) * Wd[k];
    #pragma unroll
    for (int off = 32; off > 0; off >>= 1) s += __shfl_down(s, off);
    if (lane == 0) out[b] = sigf(s + bd[0]);
}

extern "C" void kernel_launch(void* const* d_in, const int* in_sizes, int n_in,
                              void* d_out, int out_size, void* d_ws, size_t ws_size,
                              hipStream_t stream) {
    const int*   tokens = (const int*)  d_in[0];
    const float* emb    = (const float*)d_in[1];
    const float* W0     = (const float*)d_in[2];
    const float* U0     = (const float*)d_in[3];
    const float* b0     = (const float*)d_in[4];
    const float* W1     = (const float*)d_in[5];
    const float* U1     = (const float*)d_in[6];
    const float* b1     = (const float*)d_in[7];
    const float* Wd     = (const float*)d_in[8];
    const float* bd     = (const float*)d_in[9];
    float* out = (float*)d_out;

    const size_t oWt0 = 0;
    const size_t oWt1 = (size_t)G4 * 768 * 2;                 // 3,145,728
    const size_t oH0  = oWt1 + (size_t)G4 * 1024 * 2;         // 7,340,032
    const size_t oH1  = oH0 + (size_t)2 * BB * UU * 2;
    const size_t oBar = oH1 + (size_t)2 * BB * UU * 2;
    const size_t oX   = oBar + 4096;
    const size_t needFull = oX + (size_t)TT * BB * EE * 2;    // ~41.9 MB
    int use_xbf = (ws_size >= needFull) ? 1 : 0;

    unsigned short* Wt0p = (unsigned short*)((char*)d_ws + oWt0);
    unsigned short* Wt1p = (unsigned short*)((char*)d_ws + oWt1);
    unsigned short* h0p  = (unsigned short*)((char*)d_ws + oH0);
    unsigned short* h1p  = (unsigned short*)((char*)d_ws + oH1);
    unsigned int*   barp = (unsigned int*)  ((char*)d_ws + oBar);
    unsigned short* xbfp = (unsigned short*)((char*)d_ws + oX);

    hipMemsetAsync((char*)d_ws + oH0, 0, (oBar + 4096) - oH0, stream);

    wtrans<<<dim3(G4 / 32, EE / 32), dim3(32, 8), 0, stream>>>(W0, EE, Wt0p, 768, 0);
    wtrans<<<dim3(G4 / 32, UU / 32), dim3(32, 8), 0, stream>>>(U0, UU, Wt0p, 768, 256);
    wtrans<<<dim3(G4 / 32, UU / 32), dim3(32, 8), 0, stream>>>(W1, UU, Wt1p, 1024, 0);
    wtrans<<<dim3(G4 / 32, UU / 32), dim3(32, 8), 0, stream>>>(U1, UU, Wt1p, 1024, 512);

    if (use_xbf)
        xgather<<<dim3(BB * TT), dim3(64), 0, stream>>>(tokens, emb, xbfp);

    {
        const size_t shmem = 131072 + 2048 + 256;   // 133,376 B dynamic LDS
        hipFuncSetAttribute((const void*)rnn_persist,
                            hipFuncAttributeMaxDynamicSharedMemorySize, (int)shmem);
        void* args[] = {(void*)&Wt0p, (void*)&Wt1p, (void*)&xbfp,
                        (void*)&tokens, (void*)&emb, (void*)&b0, (void*)&b1,
                        (void*)&h0p, (void*)&h1p, (void*)&barp, (void*)&use_xbf};
        hipLaunchCooperativeKernel((const void*)rnn_persist, dim3(256), dim3(256),
                                   args, shmem, stream);
    }

    dense_out<<<dim3(BB), dim3(64), 0, stream>>>(h1p, Wd, bd, out);
}